// Round 11
// baseline (6810.012 us; speedup 1.0000x reference)
//
#include <hip/hip_runtime.h>

#define DEV static __device__ __forceinline__

typedef _Float16 h2 __attribute__((ext_vector_type(2)));

DEV float fdot2f(h2 a, h2 b, float c) {
#if __has_builtin(__builtin_amdgcn_fdot2)
  return __builtin_amdgcn_fdot2(a, b, c, false);
#else
  return c + (float)a.x * (float)b.x + (float)a.y * (float)b.y;
#endif
}

// LayerNorm over 3 elements: (x-m)/sqrt(v+eps)*g + b
DEV void ln3(float& a, float& b, float& c, const float* g, const float* bt) {
  float m = (a + b + c) * (1.0f / 3.0f);
  float d0 = a - m, d1 = b - m, d2 = c - m;
  float v = (d0 * d0 + d1 * d1 + d2 * d2) * (1.0f / 3.0f);
  float rs = rsqrtf(v + 1e-5f);
  a = fmaf(d0 * rs, g[0], bt[0]);
  b = fmaf(d1 * rs, g[1], bt[1]);
  c = fmaf(d2 * rs, g[2], bt[2]);
}

DEV unsigned pkh2(float a, float b) {
  h2 v = {(_Float16)a, (_Float16)b};
  return __builtin_bit_cast(unsigned, v);
}

// ---------------------------------------------------------------------------
// Prepack (round-6 layout):
//  FAB[l] = 2048 x uint4 contiguous per layer:
//    [0..1023]    { pk(w1[2jp][d],w1[2jp+1][d]) d=0..2, pk(b1 pair) }
//    [1024..2047] { pk(w2[d][2jp],w2[d][2jp+1]) d=0..2, 0 }
//  SM[l][128] fp32 attn/LN scalars at float offset 196608 | GLOB[16] after
// ---------------------------------------------------------------------------
__global__ void __launch_bounds__(256) prepack_kernel(
    const float* ea_w, const float* ea_b, const float* ea_ow, const float* ea_ob,
    const float* el1g, const float* el1b, const float* el2g, const float* el2b,
    const float* ef1w, const float* ef1b, const float* ef2w, const float* ef2b,
    const float* eng, const float* enb,
    const float* dsw, const float* dsb, const float* dsow, const float* dsob,
    const float* dcw, const float* dcb, const float* dcow, const float* dcob,
    const float* dl1g, const float* dl1b, const float* dl2g, const float* dl2b,
    const float* dl3g, const float* dl3b,
    const float* df1w, const float* df1b, const float* df2w, const float* df2b,
    const float* dng, const float* dnb,
    float* ws) {
  const int l = blockIdx.x, tid = threadIdx.x;
  const bool enc = l < 12;
  const int li = enc ? l : l - 12;
  const float* f1w = (enc ? ef1w : df1w) + li * 2048 * 3;
  const float* f1b = (enc ? ef1b : df1b) + li * 2048;
  const float* f2w = (enc ? ef2w : df2w) + li * 3 * 2048;
  uint4* FA4 = (uint4*)ws + (size_t)l * 2048;
  uint4* FB4 = FA4 + 1024;
  for (int jp = tid; jp < 1024; jp += 256) {
    const int j0 = jp * 2, j1 = j0 + 1;
    uint4 A;
    A.x = pkh2(f1w[j0 * 3 + 0], f1w[j1 * 3 + 0]);
    A.y = pkh2(f1w[j0 * 3 + 1], f1w[j1 * 3 + 1]);
    A.z = pkh2(f1w[j0 * 3 + 2], f1w[j1 * 3 + 2]);
    A.w = pkh2(f1b[j0], f1b[j1]);
    FA4[jp] = A;
    uint4 Bv;
    Bv.x = pkh2(f2w[j0], f2w[j1]);
    Bv.y = pkh2(f2w[2048 + j0], f2w[2048 + j1]);
    Bv.z = pkh2(f2w[4096 + j0], f2w[4096 + j1]);
    Bv.w = 0u;
    FB4[jp] = Bv;
  }
  float* S = ws + 196608 + l * 128;
  if (tid == 0) {
    // 0-26 qkv W | 27-35 qkv b | 36-44 ow | 45-47 ob | 48-53 ln1 g,b
    // 54-59 ln2 g,b | 60-62 ffn b2
    const float* aw = (enc ? ea_w : dsw) + li * 27;
    const float* ab = (enc ? ea_b : dsb) + li * 9;
    const float* aow = (enc ? ea_ow : dsow) + li * 9;
    const float* aob = (enc ? ea_ob : dsob) + li * 3;
    for (int i = 0; i < 27; ++i) S[i] = aw[i];
    for (int i = 0; i < 9; ++i) S[27 + i] = ab[i];
    for (int i = 0; i < 9; ++i) S[36 + i] = aow[i];
    for (int i = 0; i < 3; ++i) S[45 + i] = aob[i];
    const float* p;
    p = (enc ? el1g : dl1g) + li * 3; for (int i = 0; i < 3; ++i) S[48 + i] = p[i];
    p = (enc ? el1b : dl1b) + li * 3; for (int i = 0; i < 3; ++i) S[51 + i] = p[i];
    p = (enc ? el2g : dl2g) + li * 3; for (int i = 0; i < 3; ++i) S[54 + i] = p[i];
    p = (enc ? el2b : dl2b) + li * 3; for (int i = 0; i < 3; ++i) S[57 + i] = p[i];
    p = (enc ? ef2b : df2b) + li * 3; for (int i = 0; i < 3; ++i) S[60 + i] = p[i];
    if (!enc) {
      // 64-72 cross qW | 73-75 qb | 76-84 cross ow | 85-87 ob | 88-93 ln3 g,b
      // 94-102 kW | 103-105 kb | 106-114 vW | 115-117 vb
      const float* cw = dcw + li * 27;
      for (int i = 0; i < 9; ++i) {
        S[64 + i] = cw[i];
        S[94 + i] = cw[9 + i];
        S[106 + i] = cw[18 + i];
      }
      const float* cb = dcb + li * 9;
      for (int i = 0; i < 3; ++i) {
        S[73 + i] = cb[i];
        S[103 + i] = cb[3 + i];
        S[115 + i] = cb[6 + i];
      }
      for (int i = 0; i < 9; ++i) S[76 + i] = dcow[li * 9 + i];
      for (int i = 0; i < 3; ++i) S[85 + i] = dcob[li * 3 + i];
      p = dl3g + li * 3; for (int i = 0; i < 3; ++i) S[88 + i] = p[i];
      p = dl3b + li * 3; for (int i = 0; i < 3; ++i) S[91 + i] = p[i];
    }
  }
  if (l == 0 && tid == 1) {
    float* G = ws + 196608 + 24 * 128;
    for (int i = 0; i < 3; ++i) {
      G[i] = eng[i]; G[3 + i] = enb[i];
      G[6 + i] = dng[i]; G[9 + i] = dnb[i];
    }
  }
}

// Packed-f16 FFN for NR rows (rows = wave + 16*i), weights streamed from L2.
template <int NR>
DEV void ffn_core(const uint4* FA,
                  const float (&X0)[4], const float (&X1)[4], const float (&X2)[4],
                  float (&acc)[4][3], int lane) {
  h2 xd0[NR], xd1[NR], xd2[NR];
#pragma unroll
  for (int i = 0; i < NR; ++i) {
    xd0[i] = h2{(_Float16)X0[i], (_Float16)X0[i]};
    xd1[i] = h2{(_Float16)X1[i], (_Float16)X1[i]};
    xd2[i] = h2{(_Float16)X2[i], (_Float16)X2[i]};
  }
#pragma unroll
  for (int i = 0; i < NR; ++i) { acc[i][0] = 0.f; acc[i][1] = 0.f; acc[i][2] = 0.f; }
  const h2 z = {(_Float16)0, (_Float16)0};
#pragma unroll 4
  for (int kk = 0; kk < 16; ++kk) {
    const int jp = lane + (kk << 6);
    uint4 a = FA[jp];
    uint4 c = FA[1024 + jp];
    h2 wa0 = __builtin_bit_cast(h2, a.x), wa1 = __builtin_bit_cast(h2, a.y);
    h2 wa2 = __builtin_bit_cast(h2, a.z), bb = __builtin_bit_cast(h2, a.w);
    h2 wc0 = __builtin_bit_cast(h2, c.x), wc1 = __builtin_bit_cast(h2, c.y);
    h2 wc2 = __builtin_bit_cast(h2, c.z);
#pragma unroll
    for (int i = 0; i < NR; ++i) {
      h2 t = wa0 * xd0[i] + wa1 * xd1[i] + wa2 * xd2[i] + bb;
      t = __builtin_elementwise_max(t, z);
      acc[i][0] = fdot2f(wc0, t, acc[i][0]);
      acc[i][1] = fdot2f(wc1, t, acc[i][1]);
      acc[i][2] = fdot2f(wc2, t, acc[i][2]);
    }
  }
#pragma unroll
  for (int m = 1; m < 64; m <<= 1) {
#pragma unroll
    for (int i = 0; i < NR; ++i) {
      acc[i][0] += __shfl_xor(acc[i][0], m, 64);
      acc[i][1] += __shfl_xor(acc[i][1], m, 64);
      acc[i][2] += __shfl_xor(acc[i][2], m, 64);
    }
  }
}

// ---------------------------------------------------------------------------
// One layer, LDS-lean. DEC (5 barriers): P1 qkv (packed kv2/kq) | P2 self
// partials (12 waves, b64 K/V, arithmetic multiplicity) | P3 redundant-C1 +
// cross partials (12 waves, transposed b64 partials) | P3b X-combine (1 wave,
// lane=row) | P4 FFN (16 waves, b128 xs). ENC (4 barriers): P1|P2|P3b|P4.
// Zero-rep row R-1 handled via p==t => e*=(64-t); pad keys p>t => e=0.
// ---------------------------------------------------------------------------
template <bool DEC>
DEV void run_layer(const float* sm, const uint4* FA, const float2* ckv2,
                   float4* h4, float4* hln4, float4* xs4,
                   float (*kq)[5], float2 (*kv2)[64],
                   float2 (*p1t)[64], float2 (*p2t)[64],
                   float4* o_s4, const float* glob,
                   int R, int t, bool from_os, bool wpred,
                   int wave, int lane, int tid) {
  // ---- P1: QKV, packed; thread (r,o): o<3 -> q_o, o in 3..5 -> (k,v)_head ----
  {
    const int r = tid >> 4, o = tid & 15;
    if (o < 6) {
      float x0, x1, x2;
      if (DEC && from_os) {
        float4 xv = o_s4[r];
        const bool real = r < t;
        x0 = real ? xv.x : 0.f; x1 = real ? xv.y : 0.f; x2 = real ? xv.z : 0.f;
      } else {
        float4 xv = h4[r];
        x0 = xv.x; x1 = xv.y; x2 = xv.z;
        if (DEC && r >= R) { x0 = 0.f; x1 = 0.f; x2 = 0.f; }  // pads deterministic
      }
      if (o < 3) {
        kq[r][o] = fmaf(sm[o * 3], x0,
                   fmaf(sm[o * 3 + 1], x1, fmaf(sm[o * 3 + 2], x2, sm[27 + o])));
      } else {
        const int hd = o - 3;
        float k = fmaf(sm[9 + hd * 3], x0,
                  fmaf(sm[9 + hd * 3 + 1], x1, fmaf(sm[9 + hd * 3 + 2], x2, sm[30 + hd])));
        float v = fmaf(sm[18 + hd * 3], x0,
                  fmaf(sm[18 + hd * 3 + 1], x1, fmaf(sm[18 + hd * 3 + 2], x2, sm[33 + hd])));
        kv2[hd][r] = float2{k, v};
      }
    } else if (o == 6 && DEC && from_os) {
      // publish this step's residual-stream input into h4
      float4 xv = o_s4[r];
      const bool real = r < t;
      float4 hx;
      hx.x = real ? xv.x : 0.f; hx.y = real ? xv.y : 0.f;
      hx.z = real ? xv.z : 0.f; hx.w = 0.f;
      h4[r] = hx;
    }
  }
  __syncthreads();
  // ---- P2: self-attn partials; wave = hd + 3*chunk; b64 K/V reads ----
  if (wave < 12) {
    const int hd = wave % 3, c = wave / 3;
    const int p0 = c * 16;
    const float q = kq[lane][hd] * 1.44269504f;
    float den = 0.f, num = 0.f;
#pragma unroll
    for (int pp = 0; pp < 16; ++pp) {
      const int p = p0 + pp;
      float2 kv = kv2[hd][p];
      float e = exp2f(q * kv.x);
      if (DEC) {
        e = (p > t) ? 0.f : e;                       // pad keys dead
        e = (p == t) ? e * (float)(64 - t) : e;      // zero-rep multiplicity
      }
      den += e;
      num = fmaf(e, kv.y, num);
    }
    p1t[wave][lane] = float2{den, num};
  }
  __syncthreads();
  if (DEC) {
    // ---- P3: redundant C1 (lane=row) + cross-q + cross partials ----
    if (wave < 12) {
      const int hd = wave % 3, c = wave / 3;
      float2 P[12];
#pragma unroll
      for (int w2 = 0; w2 < 12; ++w2) P[w2] = p1t[w2][lane];
      float d0 = P[0].x + P[3].x + P[6].x + P[9].x;
      float n0 = P[0].y + P[3].y + P[6].y + P[9].y;
      float d1 = P[1].x + P[4].x + P[7].x + P[10].x;
      float n1 = P[1].y + P[4].y + P[7].y + P[10].y;
      float d2 = P[2].x + P[5].x + P[8].x + P[11].x;
      float n2 = P[2].y + P[5].y + P[8].y + P[11].y;
      float oh0 = __fdividef(n0, d0), oh1 = __fdividef(n1, d1), oh2 = __fdividef(n2, d2);
      float4 hx = h4[lane];
      float a0 = fmaf(sm[36], oh0, fmaf(sm[37], oh1, fmaf(sm[38], oh2, sm[45]))) + hx.x;
      float a1 = fmaf(sm[39], oh0, fmaf(sm[40], oh1, fmaf(sm[41], oh2, sm[46]))) + hx.y;
      float a2 = fmaf(sm[42], oh0, fmaf(sm[43], oh1, fmaf(sm[44], oh2, sm[47]))) + hx.z;
      ln3(a0, a1, a2, sm + 48, sm + 51);
      if (wave == 0) hln4[lane] = float4{a0, a1, a2, 0.f};
      float q = fmaf(sm[64 + hd * 3], a0,
                fmaf(sm[64 + hd * 3 + 1], a1,
                fmaf(sm[64 + hd * 3 + 2], a2, sm[73 + hd]))) * 1.44269504f;
      const int p0 = c * 16;
      float den = 0.f, num = 0.f;
#pragma unroll
      for (int pp = 0; pp < 16; ++pp) {
        float2 kv = ckv2[hd * 64 + p0 + pp];
        float e = exp2f(q * kv.x);
        den += e;
        num = fmaf(e, kv.y, num);
      }
      p2t[wave][lane] = float2{den, num};
    }
    __syncthreads();
  }
  // ---- P3b: X-combine, one wave, lane = row ----
  if (wave == 0) {
    const float2(*pt)[64] = DEC ? p2t : p1t;
    float2 P[12];
#pragma unroll
    for (int w2 = 0; w2 < 12; ++w2) P[w2] = pt[w2][lane];
    float d0 = P[0].x + P[3].x + P[6].x + P[9].x;
    float n0 = P[0].y + P[3].y + P[6].y + P[9].y;
    float d1 = P[1].x + P[4].x + P[7].x + P[10].x;
    float n1 = P[1].y + P[4].y + P[7].y + P[10].y;
    float d2 = P[2].x + P[5].x + P[8].x + P[11].x;
    float n2 = P[2].y + P[5].y + P[8].y + P[11].y;
    float oh0 = __fdividef(n0, d0), oh1 = __fdividef(n1, d1), oh2 = __fdividef(n2, d2);
    const float* ow = DEC ? sm + 76 : sm + 36;
    const float* ob = DEC ? sm + 85 : sm + 45;
    const float* lg = DEC ? sm + 54 : sm + 48;
    const float* lb = DEC ? sm + 57 : sm + 51;
    float4 rx = DEC ? hln4[lane] : h4[lane];
    float a0 = fmaf(ow[0], oh0, fmaf(ow[1], oh1, fmaf(ow[2], oh2, ob[0]))) + rx.x;
    float a1 = fmaf(ow[3], oh0, fmaf(ow[4], oh1, fmaf(ow[5], oh2, ob[1]))) + rx.y;
    float a2 = fmaf(ow[6], oh0, fmaf(ow[7], oh1, fmaf(ow[8], oh2, ob[2]))) + rx.z;
    ln3(a0, a1, a2, lg, lb);
    xs4[lane] = float4{a0, a1, a2, 0.f};
  }
  __syncthreads();
  // ---- P4: packed FFN + final LN; rows = wave + 16*i ----
  {
    const int nr = (wave < R) ? (1 + (R - 1 - wave) / 16) : 0;
    if (nr > 0) {
      float X0[4], X1[4], X2[4];
#pragma unroll
      for (int i = 0; i < 4; ++i) {
        X0[i] = 0.f; X1[i] = 0.f; X2[i] = 0.f;
        if (i < nr) {
          float4 xv = xs4[wave + 16 * i];
          X0[i] = xv.x; X1[i] = xv.y; X2[i] = xv.z;
        }
      }
      float acc[4][3];
      switch (nr) {
        case 1: ffn_core<1>(FA, X0, X1, X2, acc, lane); break;
        case 2: ffn_core<2>(FA, X0, X1, X2, acc, lane); break;
        case 3: ffn_core<3>(FA, X0, X1, X2, acc, lane); break;
        default: ffn_core<4>(FA, X0, X1, X2, acc, lane); break;
      }
      if (lane == 0) {
        const float* fg = DEC ? sm + 88 : sm + 54;
        const float* fb = DEC ? sm + 91 : sm + 57;
#pragma unroll
        for (int i = 0; i < 4; ++i) {
          if (i < nr) {
            const int r = wave + 16 * i;
            float y0 = acc[i][0] + sm[60] + X0[i];
            float y1 = acc[i][1] + sm[61] + X1[i];
            float y2 = acc[i][2] + sm[62] + X2[i];
            ln3(y0, y1, y2, fg, fb);
            h4[r] = float4{y0, y1, y2, 0.f};
            if (DEC && wpred && r == R - 1) {  // pred[t] = dec_norm(zero-rep)
              ln3(y0, y1, y2, glob + 6, glob + 9);
              o_s4[t] = float4{y0, y1, y2, 0.f};
            }
          }
        }
      }
    }
    __syncthreads();
  }
}

// ---------------------------------------------------------------------------
// Main kernel: one block per batch element. Encoder -> cross K/V precompute
// -> 63 autoregressive decode steps with zero-row dedup -> output transpose.
// ---------------------------------------------------------------------------
__global__ void __launch_bounds__(1024) tf_kernel(const float* src, const float* angle,
                                                  const float* ws, float* out) {
  __shared__ float small_s[24][128];
  __shared__ float glob[16];
  __shared__ __align__(16) float4 h4[64];
  __shared__ __align__(16) float4 hln4[64];
  __shared__ __align__(16) float4 xs4[64];
  __shared__ __align__(16) float4 o_s4[64];
  __shared__ float kq[64][5];
  __shared__ __align__(8) float2 kv2[3][64];
  __shared__ __align__(8) float2 p1t[12][64];
  __shared__ __align__(8) float2 p2t[12][64];
  __shared__ __align__(8) float2 ckcv2[12][3 * 64];  // [layer][head*64+pos](k,v)
  const int b = blockIdx.x;
  const int tid = threadIdx.x, wave = tid >> 6, lane = tid & 63;
  const uint4* FABg = (const uint4*)ws;
  const float* SM = ws + 196608;
  const float* GB = SM + 24 * 128;
  for (int i = tid; i < 24 * 128; i += 1024) ((float*)small_s)[i] = SM[i];
  if (tid < 16) glob[tid] = GB[tid];
  if (tid < 64) {
    float x0 = src[b * 128 + tid];
    float x1 = src[b * 128 + 64 + tid];
    float x2 = angle[b];
    h4[tid] = float4{x0, x1, x2, 0.f};
    o_s4[tid] = (tid == 0) ? float4{x0, x1, x2, 0.f} : float4{0.f, 0.f, 0.f, 0.f};
  }
  __syncthreads();
  // ---- encoder (R=64) ----
  for (int l = 0; l < 12; ++l)
    run_layer<false>(small_s[l], FABg + (size_t)l * 2048, nullptr,
                     h4, hln4, xs4, kq, kv2, p1t, p2t, o_s4, glob,
                     64, 0, false, false, wave, lane, tid);
  // final encoder LN -> mem (in place in h4)
  if (tid < 64) {
    float4 hx = h4[tid];
    float a = hx.x, bb = hx.y, c = hx.z;
    ln3(a, bb, c, glob + 0, glob + 3);
    h4[tid] = float4{a, bb, c, 0.f};
  }
  __syncthreads();
  // ---- precompute cross-attn K/V per decoder layer (packed float2) ----
  if (wave < 12) {
    const float* sm = small_s[12 + wave];
    float4 hx = h4[lane];
    float m0 = hx.x, m1 = hx.y, m2 = hx.z;
#pragma unroll
    for (int hd = 0; hd < 3; ++hd) {
      float k = fmaf(sm[94 + hd * 3], m0,
                fmaf(sm[94 + hd * 3 + 1], m1, fmaf(sm[94 + hd * 3 + 2], m2, sm[103 + hd])));
      float v = fmaf(sm[106 + hd * 3], m0,
                fmaf(sm[106 + hd * 3 + 1], m1, fmaf(sm[106 + hd * 3 + 2], m2, sm[115 + hd])));
      ckcv2[wave][hd * 64 + lane] = float2{k, v};
    }
  }
  __syncthreads();
  // ---- autoregressive decode: step t fills o_s4[t] ----
  for (int t = 1; t < 64; ++t) {
    const int R = t + 1;
    for (int li = 0; li < 12; ++li)
      run_layer<true>(small_s[12 + li], FABg + (size_t)(12 + li) * 2048,
                      ckcv2[li],
                      h4, hln4, xs4, kq, kv2, p1t, p2t, o_s4, glob, R, t,
                      /*from_os=*/li == 0, /*wpred=*/li == 11, wave, lane, tid);
  }
  // ---- output: [B,3,T] ----
  if (tid < 192) {
    int d = tid / 64, tt = tid % 64;
    out[b * 192 + tid] = ((const float*)o_s4)[tt * 4 + d];
  }
}

extern "C" void kernel_launch(void* const* d_in, const int* in_sizes, int n_in,
                              void* d_out, int out_size, void* d_ws, size_t ws_size,
                              hipStream_t stream) {
  (void)in_sizes; (void)n_in; (void)out_size; (void)ws_size;
  float* ws = (float*)d_ws;
  prepack_kernel<<<24, 256, 0, stream>>>(
      (const float*)d_in[2], (const float*)d_in[3], (const float*)d_in[4], (const float*)d_in[5],
      (const float*)d_in[6], (const float*)d_in[7], (const float*)d_in[8], (const float*)d_in[9],
      (const float*)d_in[10], (const float*)d_in[11], (const float*)d_in[12], (const float*)d_in[13],
      (const float*)d_in[14], (const float*)d_in[15],
      (const float*)d_in[16], (const float*)d_in[17], (const float*)d_in[18], (const float*)d_in[19],
      (const float*)d_in[20], (const float*)d_in[21], (const float*)d_in[22], (const float*)d_in[23],
      (const float*)d_in[24], (const float*)d_in[25], (const float*)d_in[26], (const float*)d_in[27],
      (const float*)d_in[28], (const float*)d_in[29],
      (const float*)d_in[30], (const float*)d_in[31], (const float*)d_in[32], (const float*)d_in[33],
      (const float*)d_in[34], (const float*)d_in[35],
      ws);
  tf_kernel<<<32, 1024, 0, stream>>>((const float*)d_in[0], (const float*)d_in[1], ws,
                                     (float*)d_out);
}

// Round 13
// 6543.763 us; speedup vs baseline: 1.0407x; 1.0407x over previous
//
#include <hip/hip_runtime.h>

#define DEV static __device__ __forceinline__

typedef _Float16 h2 __attribute__((ext_vector_type(2)));

DEV float fdot2f(h2 a, h2 b, float c) {
#if __has_builtin(__builtin_amdgcn_fdot2)
  return __builtin_amdgcn_fdot2(a, b, c, false);
#else
  return c + (float)a.x * (float)b.x + (float)a.y * (float)b.y;
#endif
}

// LayerNorm over 3 elements: (x-m)/sqrt(v+eps)*g + b
DEV void ln3(float& a, float& b, float& c, const float* g, const float* bt) {
  float m = (a + b + c) * (1.0f / 3.0f);
  float d0 = a - m, d1 = b - m, d2 = c - m;
  float v = (d0 * d0 + d1 * d1 + d2 * d2) * (1.0f / 3.0f);
  float rs = rsqrtf(v + 1e-5f);
  a = fmaf(d0 * rs, g[0], bt[0]);
  b = fmaf(d1 * rs, g[1], bt[1]);
  c = fmaf(d2 * rs, g[2], bt[2]);
}

DEV unsigned pkh2(float a, float b) {
  h2 v = {(_Float16)a, (_Float16)b};
  return __builtin_bit_cast(unsigned, v);
}

// ---------------------------------------------------------------------------
// Prepack (round-6 layout):
//  FAB[l] = 2048 x uint4 contiguous per layer:
//    [0..1023]    { pk(w1[2jp][d],w1[2jp+1][d]) d=0..2, pk(b1 pair) }
//    [1024..2047] { pk(w2[d][2jp],w2[d][2jp+1]) d=0..2, 0 }
//  SM[l][128] fp32 attn/LN scalars at float offset 196608 | GLOB[16] after
// ---------------------------------------------------------------------------
__global__ void __launch_bounds__(256) prepack_kernel(
    const float* ea_w, const float* ea_b, const float* ea_ow, const float* ea_ob,
    const float* el1g, const float* el1b, const float* el2g, const float* el2b,
    const float* ef1w, const float* ef1b, const float* ef2w, const float* ef2b,
    const float* eng, const float* enb,
    const float* dsw, const float* dsb, const float* dsow, const float* dsob,
    const float* dcw, const float* dcb, const float* dcow, const float* dcob,
    const float* dl1g, const float* dl1b, const float* dl2g, const float* dl2b,
    const float* dl3g, const float* dl3b,
    const float* df1w, const float* df1b, const float* df2w, const float* df2b,
    const float* dng, const float* dnb,
    float* ws) {
  const int l = blockIdx.x, tid = threadIdx.x;
  const bool enc = l < 12;
  const int li = enc ? l : l - 12;
  const float* f1w = (enc ? ef1w : df1w) + li * 2048 * 3;
  const float* f1b = (enc ? ef1b : df1b) + li * 2048;
  const float* f2w = (enc ? ef2w : df2w) + li * 3 * 2048;
  uint4* FA4 = (uint4*)ws + (size_t)l * 2048;
  uint4* FB4 = FA4 + 1024;
  for (int jp = tid; jp < 1024; jp += 256) {
    const int j0 = jp * 2, j1 = j0 + 1;
    uint4 A;
    A.x = pkh2(f1w[j0 * 3 + 0], f1w[j1 * 3 + 0]);
    A.y = pkh2(f1w[j0 * 3 + 1], f1w[j1 * 3 + 1]);
    A.z = pkh2(f1w[j0 * 3 + 2], f1w[j1 * 3 + 2]);
    A.w = pkh2(f1b[j0], f1b[j1]);
    FA4[jp] = A;
    uint4 Bv;
    Bv.x = pkh2(f2w[j0], f2w[j1]);
    Bv.y = pkh2(f2w[2048 + j0], f2w[2048 + j1]);
    Bv.z = pkh2(f2w[4096 + j0], f2w[4096 + j1]);
    Bv.w = 0u;
    FB4[jp] = Bv;
  }
  float* S = ws + 196608 + l * 128;
  if (tid == 0) {
    // 0-26 qkv W | 27-35 qkv b | 36-44 ow | 45-47 ob | 48-53 ln1 g,b
    // 54-59 ln2 g,b | 60-62 ffn b2
    const float* aw = (enc ? ea_w : dsw) + li * 27;
    const float* ab = (enc ? ea_b : dsb) + li * 9;
    const float* aow = (enc ? ea_ow : dsow) + li * 9;
    const float* aob = (enc ? ea_ob : dsob) + li * 3;
    for (int i = 0; i < 27; ++i) S[i] = aw[i];
    for (int i = 0; i < 9; ++i) S[27 + i] = ab[i];
    for (int i = 0; i < 9; ++i) S[36 + i] = aow[i];
    for (int i = 0; i < 3; ++i) S[45 + i] = aob[i];
    const float* p;
    p = (enc ? el1g : dl1g) + li * 3; for (int i = 0; i < 3; ++i) S[48 + i] = p[i];
    p = (enc ? el1b : dl1b) + li * 3; for (int i = 0; i < 3; ++i) S[51 + i] = p[i];
    p = (enc ? el2g : dl2g) + li * 3; for (int i = 0; i < 3; ++i) S[54 + i] = p[i];
    p = (enc ? el2b : dl2b) + li * 3; for (int i = 0; i < 3; ++i) S[57 + i] = p[i];
    p = (enc ? ef2b : df2b) + li * 3; for (int i = 0; i < 3; ++i) S[60 + i] = p[i];
    if (!enc) {
      // 64-72 cross qW | 73-75 qb | 76-84 cross ow | 85-87 ob | 88-93 ln3 g,b
      // 94-102 kW | 103-105 kb | 106-114 vW | 115-117 vb
      const float* cw = dcw + li * 27;
      for (int i = 0; i < 9; ++i) {
        S[64 + i] = cw[i];
        S[94 + i] = cw[9 + i];
        S[106 + i] = cw[18 + i];
      }
      const float* cb = dcb + li * 9;
      for (int i = 0; i < 3; ++i) {
        S[73 + i] = cb[i];
        S[103 + i] = cb[3 + i];
        S[115 + i] = cb[6 + i];
      }
      for (int i = 0; i < 9; ++i) S[76 + i] = dcow[li * 9 + i];
      for (int i = 0; i < 3; ++i) S[85 + i] = dcob[li * 3 + i];
      p = dl3g + li * 3; for (int i = 0; i < 3; ++i) S[88 + i] = p[i];
      p = dl3b + li * 3; for (int i = 0; i < 3; ++i) S[91 + i] = p[i];
    }
  }
  if (l == 0 && tid == 1) {
    float* G = ws + 196608 + 24 * 128;
    for (int i = 0; i < 3; ++i) {
      G[i] = eng[i]; G[3 + i] = enb[i];
      G[6 + i] = dng[i]; G[9 + i] = dnb[i];
    }
  }
}

// Packed-f16 FFN for NR rows (rows = wave + 16*i); kk=0,1 tiles arrive
// prefetched in registers (issued at layer entry, completed by P1/P2).
template <int NR>
DEV void ffn_core(const uint4* FA, uint4 pa0, uint4 pc0, uint4 pa1, uint4 pc1,
                  const float (&X0)[4], const float (&X1)[4], const float (&X2)[4],
                  float (&acc)[4][3], int lane) {
  h2 xd0[NR], xd1[NR], xd2[NR];
#pragma unroll
  for (int i = 0; i < NR; ++i) {
    xd0[i] = h2{(_Float16)X0[i], (_Float16)X0[i]};
    xd1[i] = h2{(_Float16)X1[i], (_Float16)X1[i]};
    xd2[i] = h2{(_Float16)X2[i], (_Float16)X2[i]};
  }
#pragma unroll
  for (int i = 0; i < NR; ++i) { acc[i][0] = 0.f; acc[i][1] = 0.f; acc[i][2] = 0.f; }
  const h2 z = {(_Float16)0, (_Float16)0};
  auto step = [&](uint4 a, uint4 c) {
    h2 wa0 = __builtin_bit_cast(h2, a.x), wa1 = __builtin_bit_cast(h2, a.y);
    h2 wa2 = __builtin_bit_cast(h2, a.z), bb = __builtin_bit_cast(h2, a.w);
    h2 wc0 = __builtin_bit_cast(h2, c.x), wc1 = __builtin_bit_cast(h2, c.y);
    h2 wc2 = __builtin_bit_cast(h2, c.z);
#pragma unroll
    for (int i = 0; i < NR; ++i) {
      h2 t = wa0 * xd0[i] + wa1 * xd1[i] + wa2 * xd2[i] + bb;
      t = __builtin_elementwise_max(t, z);
      acc[i][0] = fdot2f(wc0, t, acc[i][0]);
      acc[i][1] = fdot2f(wc1, t, acc[i][1]);
      acc[i][2] = fdot2f(wc2, t, acc[i][2]);
    }
  };
  step(pa0, pc0);
  step(pa1, pc1);
#pragma unroll 4
  for (int kk = 2; kk < 16; ++kk) {
    const int jp = lane + (kk << 6);
    step(FA[jp], FA[1024 + jp]);
  }
#pragma unroll
  for (int m = 1; m < 64; m <<= 1) {
#pragma unroll
    for (int i = 0; i < NR; ++i) {
      acc[i][0] += __shfl_xor(acc[i][0], m, 64);
      acc[i][1] += __shfl_xor(acc[i][1], m, 64);
      acc[i][2] += __shfl_xor(acc[i][2], m, 64);
    }
  }
}

// ---------------------------------------------------------------------------
// One layer. DEC: [P1 qkv (only when do_p1)] | P2 self partials | P3
// redundant-C1 + cross partials | P4 combine + FFN + final LN + fused
// NEXT-layer QKV append (weights smn; skipped when smn==nullptr).
// ENC skips P3. Barriers/layer: 3 (DEC,l>0), 4 (DEC,l==0), 2/3 (ENC).
// kvq row stride 13: q0..2 [3] k0..2(4-6) mult(7) v0..2(8-10).
// ---------------------------------------------------------------------------
template <bool DEC>
DEV void run_layer(const float* sm, const float* smn, const uint4* FA,
                   const float (*ckv)[8],
                   float (*h)[5], float (*hln)[5], float* kvq,
                   float (*p1)[25], float (*p2)[25],
                   float (*o_s)[5], const float* glob,
                   int R, int t, bool do_p1, bool from_os, bool wpred,
                   int wave, int lane, int tid) {
  // prefetch first two FFN weight tiles (complete during P1/P2 barriers)
  uint4 pa0 = FA[lane], pc0 = FA[1024 + lane];
  uint4 pa1 = FA[64 + lane], pc1 = FA[1024 + 64 + lane];
  // ---- P1: QKV; thread (r,o) computes one projection output ----
  if (do_p1) {
    const int r = tid >> 4, o = tid & 15;
    if (r < R && o <= 9) {
      float x0, x1, x2;
      if (DEC && from_os) {
        const bool real = r < t;  // rows >= t are the zero rep
        x0 = real ? o_s[r][0] : 0.f;
        x1 = real ? o_s[r][1] : 0.f;
        x2 = real ? o_s[r][2] : 0.f;
      } else {
        x0 = h[r][0]; x1 = h[r][1]; x2 = h[r][2];
      }
      if (o < 9) {
        float v = fmaf(sm[o * 3], x0,
                  fmaf(sm[o * 3 + 1], x1, fmaf(sm[o * 3 + 2], x2, sm[27 + o])));
        kvq[r * 13 + o + o / 3] = v;
      } else {  // o == 9: key multiplicity; publish x into h for layer-0
        kvq[r * 13 + 7] = (DEC && r == R - 1 && t > 0) ? (float)(64 - t) : 1.0f;
        if (DEC && from_os) { h[r][0] = x0; h[r][1] = x1; h[r][2] = x2; }
      }
    }
    if (DEC && o == 9 && r >= R) kvq[r * 13 + 7] = 0.f;  // pad: dead keys
    __syncthreads();
  }
  // ---- P2: self-attn partials; wave = hd + 3*chunk; full 16-key unroll ----
  if (wave < 12) {
    const int hd = wave % 3, c = wave / 3;
    const int p0 = c * 16;
    float den = 0.f, num = 0.f;
    if (p0 < R) {
      const float q = kvq[lane * 13 + hd] * 1.44269504f;
#pragma unroll
      for (int pp = 0; pp < 16; ++pp) {
        const int p = p0 + pp;
        float e = exp2f(q * kvq[p * 13 + 4 + hd]);
        if (DEC) e *= kvq[p * 13 + 7];  // mult (0 for pad rows)
        den += e;
        num = fmaf(e, kvq[p * 13 + 8 + hd], num);
      }
    }
    p1[lane][2 * wave] = den;
    p1[lane][2 * wave + 1] = num;
  }
  __syncthreads();
  if (DEC) {
    // ---- P3: redundant C1 per lane-row + cross-q + cross partials ----
    if (wave < 12) {
      const int r = lane, hd = wave % 3, c = wave / 3;
      float d0 = p1[r][0] + p1[r][6] + p1[r][12] + p1[r][18];
      float n0 = p1[r][1] + p1[r][7] + p1[r][13] + p1[r][19];
      float d1 = p1[r][2] + p1[r][8] + p1[r][14] + p1[r][20];
      float n1 = p1[r][3] + p1[r][9] + p1[r][15] + p1[r][21];
      float d2 = p1[r][4] + p1[r][10] + p1[r][16] + p1[r][22];
      float n2 = p1[r][5] + p1[r][11] + p1[r][17] + p1[r][23];
      float oh0 = __fdividef(n0, d0), oh1 = __fdividef(n1, d1), oh2 = __fdividef(n2, d2);
      float a0 = fmaf(sm[36], oh0, fmaf(sm[37], oh1, fmaf(sm[38], oh2, sm[45]))) + h[r][0];
      float a1 = fmaf(sm[39], oh0, fmaf(sm[40], oh1, fmaf(sm[41], oh2, sm[46]))) + h[r][1];
      float a2 = fmaf(sm[42], oh0, fmaf(sm[43], oh1, fmaf(sm[44], oh2, sm[47]))) + h[r][2];
      ln3(a0, a1, a2, sm + 48, sm + 51);
      if (wave == 0 && r < R) { hln[r][0] = a0; hln[r][1] = a1; hln[r][2] = a2; }
      float q = fmaf(sm[64 + hd * 3], a0,
                fmaf(sm[64 + hd * 3 + 1], a1,
                fmaf(sm[64 + hd * 3 + 2], a2, sm[73 + hd]))) * 1.44269504f;
      const int p0 = c * 16;
      float den = 0.f, num = 0.f;
#pragma unroll
      for (int pp = 0; pp < 16; ++pp) {
        const int p = p0 + pp;
        float e = exp2f(q * ckv[p][hd]);
        den += e;
        num = fmaf(e, ckv[p][3 + hd], num);
      }
      p2[r][2 * wave] = den;
      p2[r][2 * wave + 1] = num;
    }
    __syncthreads();
  }
  // ---- P4: combine + packed FFN + final LN + fused QKV append (smn) ----
  {
    const int nr = (wave < R) ? (1 + (R - 1 - wave) / 16) : 0;
    if (nr > 0) {
      const float(*pp)[25] = DEC ? p2 : p1;
      const float* ow = DEC ? sm + 76 : sm + 36;
      const float* ob = DEC ? sm + 85 : sm + 45;
      const float* lg = DEC ? sm + 54 : sm + 48;
      const float* lb = DEC ? sm + 57 : sm + 51;
      float X0[4], X1[4], X2[4];
#pragma unroll
      for (int i = 0; i < 4; ++i) {
        X0[i] = 0.f; X1[i] = 0.f; X2[i] = 0.f;
        if (i < nr) {
          const int rc = wave + 16 * i;
          float d0 = pp[rc][0] + pp[rc][6] + pp[rc][12] + pp[rc][18];
          float n0 = pp[rc][1] + pp[rc][7] + pp[rc][13] + pp[rc][19];
          float d1 = pp[rc][2] + pp[rc][8] + pp[rc][14] + pp[rc][20];
          float n1 = pp[rc][3] + pp[rc][9] + pp[rc][15] + pp[rc][21];
          float d2 = pp[rc][4] + pp[rc][10] + pp[rc][16] + pp[rc][22];
          float n2 = pp[rc][5] + pp[rc][11] + pp[rc][17] + pp[rc][23];
          float oh0 = __fdividef(n0, d0), oh1 = __fdividef(n1, d1), oh2 = __fdividef(n2, d2);
          float hr0, hr1, hr2;
          if (DEC) { hr0 = hln[rc][0]; hr1 = hln[rc][1]; hr2 = hln[rc][2]; }
          else     { hr0 = h[rc][0];   hr1 = h[rc][1];   hr2 = h[rc][2]; }
          float a0 = fmaf(ow[0], oh0, fmaf(ow[1], oh1, fmaf(ow[2], oh2, ob[0]))) + hr0;
          float a1 = fmaf(ow[3], oh0, fmaf(ow[4], oh1, fmaf(ow[5], oh2, ob[1]))) + hr1;
          float a2 = fmaf(ow[6], oh0, fmaf(ow[7], oh1, fmaf(ow[8], oh2, ob[2]))) + hr2;
          ln3(a0, a1, a2, lg, lb);
          X0[i] = a0; X1[i] = a1; X2[i] = a2;
        }
      }
      float acc[4][3];
      switch (nr) {
        case 1: ffn_core<1>(FA, pa0, pc0, pa1, pc1, X0, X1, X2, acc, lane); break;
        case 2: ffn_core<2>(FA, pa0, pc0, pa1, pc1, X0, X1, X2, acc, lane); break;
        case 3: ffn_core<3>(FA, pa0, pc0, pa1, pc1, X0, X1, X2, acc, lane); break;
        default: ffn_core<4>(FA, pa0, pc0, pa1, pc1, X0, X1, X2, acc, lane); break;
      }
      const float* fg = DEC ? sm + 88 : sm + 54;
      const float* fb = DEC ? sm + 91 : sm + 57;
#pragma unroll
      for (int i = 0; i < 4; ++i) {
        if (i < nr) {
          const int r = wave + 16 * i;
          // all lanes hold the reduced acc -> compute y redundantly
          float y0 = acc[i][0] + sm[60] + X0[i];
          float y1 = acc[i][1] + sm[61] + X1[i];
          float y2 = acc[i][2] + sm[62] + X2[i];
          ln3(y0, y1, y2, fg, fb);
          if (lane == 0) {
            h[r][0] = y0; h[r][1] = y1; h[r][2] = y2;
            if (DEC && wpred && r == R - 1) {  // pred[t] = dec_norm(zero-rep)
              float z0 = y0, z1 = y1, z2 = y2;
              ln3(z0, z1, z2, glob + 6, glob + 9);
              o_s[t][0] = z0; o_s[t][1] = z1; o_s[t][2] = z2;
            }
          }
          // fused next-layer QKV with the NEXT layer's weights (smn)
          if (smn && lane >= 9 * i && lane < 9 * i + 9) {
            const int o = lane - 9 * i;
            kvq[r * 13 + o + o / 3] =
                fmaf(smn[o * 3], y0,
                fmaf(smn[o * 3 + 1], y1, fmaf(smn[o * 3 + 2], y2, smn[27 + o])));
          }
        }
      }
    }
    __syncthreads();
  }
}

// ---------------------------------------------------------------------------
// Main kernel: one block per batch element. Encoder -> cross K/V precompute
// -> 63 autoregressive decode steps with zero-row dedup -> output transpose.
// ---------------------------------------------------------------------------
__global__ void __launch_bounds__(1024) tf_kernel(const float* src, const float* angle,
                                                  const float* ws, float* out) {
  __shared__ float small_s[24][128];
  __shared__ float glob[16];
  __shared__ float h[64][5];
  __shared__ float hln[64][5];
  __shared__ float kvq[64 * 13];
  __shared__ float p1[64][25];
  __shared__ float p2[64][25];
  __shared__ float o_s[64][5];
  __shared__ float ckcv[12][64][8];
  const int b = blockIdx.x;
  const int tid = threadIdx.x, wave = tid >> 6, lane = tid & 63;
  const uint4* FABg = (const uint4*)ws;
  const float* SM = ws + 196608;
  const float* GB = SM + 24 * 128;
  for (int i = tid; i < 24 * 128; i += 1024) ((float*)small_s)[i] = SM[i];
  if (tid < 16) glob[tid] = GB[tid];
  if (tid < 64) {
    float x0 = src[b * 128 + tid];
    float x1 = src[b * 128 + 64 + tid];
    float x2 = angle[b];
    h[tid][0] = x0; h[tid][1] = x1; h[tid][2] = x2;
    o_s[tid][0] = (tid == 0) ? x0 : 0.f;
    o_s[tid][1] = (tid == 0) ? x1 : 0.f;
    o_s[tid][2] = (tid == 0) ? x2 : 0.f;
  }
  __syncthreads();
  // ---- encoder (R=64); P1 only for layer 0 (P4 appends thereafter) ----
  for (int l = 0; l < 12; ++l)
    run_layer<false>(small_s[l], (l < 11) ? small_s[l + 1] : nullptr,
                     FABg + (size_t)l * 2048, nullptr,
                     h, hln, kvq, p1, p2, o_s, glob,
                     64, 0, /*do_p1=*/l == 0, false, false, wave, lane, tid);
  // final encoder LN -> mem (in place in h)
  if (tid < 64) {
    float a = h[tid][0], bb = h[tid][1], c = h[tid][2];
    ln3(a, bb, c, glob + 0, glob + 3);
    h[tid][0] = a; h[tid][1] = bb; h[tid][2] = c;
  }
  __syncthreads();
  // ---- precompute cross-attn K/V per decoder layer ----
  if (wave < 12) {
    const float* sm = small_s[12 + wave];
    float m0 = h[lane][0], m1 = h[lane][1], m2 = h[lane][2];
    float k0 = fmaf(sm[94], m0, fmaf(sm[95], m1, fmaf(sm[96], m2, sm[103])));
    float k1 = fmaf(sm[97], m0, fmaf(sm[98], m1, fmaf(sm[99], m2, sm[104])));
    float k2 = fmaf(sm[100], m0, fmaf(sm[101], m1, fmaf(sm[102], m2, sm[105])));
    float v0 = fmaf(sm[106], m0, fmaf(sm[107], m1, fmaf(sm[108], m2, sm[115])));
    float v1 = fmaf(sm[109], m0, fmaf(sm[110], m1, fmaf(sm[111], m2, sm[116])));
    float v2 = fmaf(sm[112], m0, fmaf(sm[113], m1, fmaf(sm[114], m2, sm[117])));
    ckcv[wave][lane][0] = k0; ckcv[wave][lane][1] = k1; ckcv[wave][lane][2] = k2;
    ckcv[wave][lane][3] = v0; ckcv[wave][lane][4] = v1; ckcv[wave][lane][5] = v2;
  }
  __syncthreads();
  // ---- autoregressive decode: step t fills o_s[t] ----
  for (int t = 1; t < 64; ++t) {
    const int R = t + 1;
    for (int li = 0; li < 12; ++li)
      run_layer<true>(small_s[12 + li], (li < 11) ? small_s[12 + li + 1] : nullptr,
                      FABg + (size_t)(12 + li) * 2048,
                      (const float(*)[8])ckcv[li],
                      h, hln, kvq, p1, p2, o_s, glob, R, t,
                      /*do_p1=*/li == 0, /*from_os=*/li == 0, /*wpred=*/li == 11,
                      wave, lane, tid);
  }
  // ---- output: [B,3,T] ----
  if (tid < 192) {
    int d = tid / 64, tt = tid % 64;
    out[b * 192 + tid] = o_s[tt][d];
  }
}

extern "C" void kernel_launch(void* const* d_in, const int* in_sizes, int n_in,
                              void* d_out, int out_size, void* d_ws, size_t ws_size,
                              hipStream_t stream) {
  (void)in_sizes; (void)n_in; (void)out_size; (void)ws_size;
  float* ws = (float*)d_ws;
  prepack_kernel<<<24, 256, 0, stream>>>(
      (const float*)d_in[2], (const float*)d_in[3], (const float*)d_in[4], (const float*)d_in[5],
      (const float*)d_in[6], (const float*)d_in[7], (const float*)d_in[8], (const float*)d_in[9],
      (const float*)d_in[10], (const float*)d_in[11], (const float*)d_in[12], (const float*)d_in[13],
      (const float*)d_in[14], (const float*)d_in[15],
      (const float*)d_in[16], (const float*)d_in[17], (const float*)d_in[18], (const float*)d_in[19],
      (const float*)d_in[20], (const float*)d_in[21], (const float*)d_in[22], (const float*)d_in[23],
      (const float*)d_in[24], (const float*)d_in[25], (const float*)d_in[26], (const float*)d_in[27],
      (const float*)d_in[28], (const float*)d_in[29],
      (const float*)d_in[30], (const float*)d_in[31], (const float*)d_in[32], (const float*)d_in[33],
      (const float*)d_in[34], (const float*)d_in[35],
      ws);
  tf_kernel<<<32, 1024, 0, stream>>>((const float*)d_in[0], (const float*)d_in[1], ws,
                                     (float*)d_out);
}